// Round 9
// baseline (727.665 us; speedup 1.0000x reference)
//
#include <hip/hip_runtime.h>
#include <hip/hip_bf16.h>

typedef __attribute__((ext_vector_type(4))) float f32x4;
typedef __attribute__((ext_vector_type(8))) _Float16 f16x8;
typedef __attribute__((ext_vector_type(4))) _Float16 f16x4;

constexpr int KCH = 64;   // chunks over S=4096
constexpr int LCH = 64;   // steps per chunk
constexpr int CH  = 8192; // channels = B*D

// ---------- ws layout (bytes), ~289 MB (proven available) ----------
// Whf f16 [g][h][o][k]: 0        .. +2097152
// summ f32x4[64][8192]: 4194304  .. +8388608
// states:               12582912 .. +8388608
// Gt f16 4 planes [chan=8192][t=4096]: 20971520 .. +268435456
constexpr size_t G_OFF   = 20971520;
constexpr size_t G_PLANE = 33554432;  // f16 elems per plane

__global__ __launch_bounds__(256) void cvt_w(const float* __restrict__ Wz,
                                             const float* __restrict__ Wi,
                                             const float* __restrict__ Wf,
                                             const float* __restrict__ Wo,
                                             _Float16* __restrict__ Whf) {
  int i = blockIdx.x * 256 + threadIdx.x;
  int flat = i << 2;
  int g = flat >> 18;
  int rest = flat & 262143;                 // [h][o][k]
  const float* src = (g == 0) ? Wz : (g == 1) ? Wi : (g == 2) ? Wf : Wo;
  f32x4 v = *(const f32x4*)(src + rest);
  f16x4 h;
#pragma unroll
  for (int j = 0; j < 4; ++j) h[j] = (_Float16)v[j];
  *(f16x4*)(Whf + flat) = h;
}

// ======================= gate GEMM (single f16) =======================
// Identical compute structure to R6 (190us, ideal traffic); epilogue packs
// 4 row-consecutive acc elems -> f16x4 8B store into channel-major Gt[g][chan][t].
__global__ __launch_bounds__(512, 6)
void gemm_f16(const float* __restrict__ x,
              const _Float16* __restrict__ Whf,
              _Float16* __restrict__ Gt) {
  extern __shared__ _Float16 sm[];
  _Float16* Af = sm;           // [128][8 chunks of 8 f16], 16 KB
  _Float16* Bf = sm + 8192;    // same, 16 KB

  int bid = blockIdx.x;                       // 8192
  int mt = (bid & 7) + ((bid >> 8) << 3);     // 0..255
  int s  = (bid >> 3) & 31;
  int g  = s & 3;
  int dt = s >> 2;                            // 0..7 -> d0 = dt*128
  int r0 = mt << 7;
  int d0 = dt << 7;
  int h  = d0 >> 8;                           // head of this d-block
  int o0 = d0 & 255;

  int tid = threadIdx.x, lane = tid & 63, wid = tid >> 6;
  int wm = wid >> 1, wn = wid & 1;            // 4m x 2n -> wave tile 32r x 64d
  int lr = lane & 15, hi2 = lane >> 4;

  const _Float16* wB = Whf + (((size_t)((g << 2) | h)) << 16);  // [256 o][256 k]

  int arow = tid >> 2;                // 4 threads per A-row
  int kq   = (tid & 3) << 4;          // 16-float k-offset
  const float* xrow = x + (size_t)(r0 + arow) * 1024 + (h << 8) + kq;

  f32x4 acc[2][4] = {};

  for (int kt = 0; kt < 4; ++kt) {
    int k0 = kt << 6;
    // ---- stage A: fp32 -> f16 -> LDS (swizzled chunks)
    {
      const float* xp = xrow + k0;
#pragma unroll
      for (int p = 0; p < 2; ++p) {
        f32x4 v0 = *(const f32x4*)(xp + p * 8);
        f32x4 v1 = *(const f32x4*)(xp + p * 8 + 4);
        f16x8 hv;
        hv[0] = (_Float16)v0.x; hv[1] = (_Float16)v0.y;
        hv[2] = (_Float16)v0.z; hv[3] = (_Float16)v0.w;
        hv[4] = (_Float16)v1.x; hv[5] = (_Float16)v1.y;
        hv[6] = (_Float16)v1.z; hv[7] = (_Float16)v1.w;
        int kc = (kq >> 3) + p;                    // chunk 0..7
        int cidx = (arow << 3) + (kc ^ (arow & 7));
        *(f16x8*)(Af + cidx * 8) = hv;
      }
    }
    // ---- stage B: global_load_lds, linear dest + inverse-swizzled source
#pragma unroll
    for (int p = 0; p < 2; ++p) {
      int c = (p << 9) + tid;           // 16B-chunk index 0..1023
      int row = c >> 3;                 // B row = d-offset 0..127
      int kcd = (c & 7) ^ (row & 7);
      const _Float16* srcp = wB + (size_t)(o0 + row) * 256 + k0 + (kcd << 3);
      __builtin_amdgcn_global_load_lds(
          (const __attribute__((address_space(1))) void*)srcp,
          (__attribute__((address_space(3))) void*)(Bf + c * 8), 16, 0, 0);
    }
    __syncthreads();
#pragma unroll
    for (int ks = 0; ks < 2; ++ks) {
      int kcf = (ks << 2) + hi2;        // frag chunk 0..7
      f16x8 af[2], bf[4];
#pragma unroll
      for (int mf = 0; mf < 2; ++mf) {
        int row = (wm << 5) + (mf << 4) + lr;
        int cidx = (row << 3) + (kcf ^ (row & 7));
        af[mf] = *(const f16x8*)(Af + cidx * 8);
      }
#pragma unroll
      for (int nf = 0; nf < 4; ++nf) {
        int row = (wn << 6) + (nf << 4) + lr;
        int cidx = (row << 3) + (kcf ^ (row & 7));
        bf[nf] = *(const f16x8*)(Bf + cidx * 8);
      }
#pragma unroll
      for (int mf = 0; mf < 2; ++mf)
#pragma unroll
        for (int nf = 0; nf < 4; ++nf)
          acc[mf][nf] = __builtin_amdgcn_mfma_f32_16x16x32_f16(af[mf], bf[nf],
                                                               acc[mf][nf], 0, 0, 0);
    }
    __syncthreads();
  }
  // ---- epilogue: C/D col=lane&15 (d), row=(lane>>4)*4+j (s). Pack j -> f16x4.
  int bb = r0 >> 12;           // batch (tiles never cross b)
  int sbase = r0 & 4095;
  _Float16* Gg = Gt + (size_t)g * G_PLANE;
#pragma unroll
  for (int mf = 0; mf < 2; ++mf)
#pragma unroll
    for (int nf = 0; nf < 4; ++nf) {
      int d = d0 + (wn << 6) + (nf << 4) + lr;
      int sx = sbase + (wm << 5) + (mf << 4) + (hi2 << 2);
      f16x4 pk;
#pragma unroll
      for (int j = 0; j < 4; ++j) pk[j] = (_Float16)acc[mf][nf][j];
      *(f16x4*)(Gg + (((size_t)((bb << 10) + d)) << 12) + sx) = pk;
    }
}

// ======================= scans over channel-major Gt =======================
// Thread owns one channel; reads contiguous f16x8 (8 timesteps) per plane,
// double-buffered. Branch-free tanh/sigmoid via __expf + __fdividef.
__global__ __launch_bounds__(256) void scan_partial_g(const _Float16* __restrict__ Gt,
                                                      f32x4* __restrict__ summ) {
  int kc = blockIdx.x >> 5;
  int cb = blockIdx.x & 31;
  int chan = cb * 256 + threadIdx.x;
  const _Float16* gz = Gt + ((size_t)chan << 12) + kc * LCH;
  const _Float16* gi = gz + G_PLANE;
  const _Float16* gf = gz + 2 * G_PLANE;

  f16x8 bzA = *(const f16x8*)(gz),     bzB = *(const f16x8*)(gz + 8);
  f16x8 biA = *(const f16x8*)(gi),     biB = *(const f16x8*)(gi + 8);
  f16x8 bfA = *(const f16x8*)(gf),     bfB = *(const f16x8*)(gf + 8);

  float m = -INFINITY, c = 0.f, n = 0.f, sf = 0.f;
#pragma unroll
  for (int sp = 0; sp < 4; ++sp) {
    // --- seg 2sp (buffer A)
    {
      f16x8 vz = bzA, vi = biA, vf = bfA;
      if (sp < 3) {
        bzA = *(const f16x8*)(gz + (sp * 2 + 2) * 8);
        biA = *(const f16x8*)(gi + (sp * 2 + 2) * 8);
        bfA = *(const f16x8*)(gf + (sp * 2 + 2) * 8);
      }
#pragma unroll
      for (int j = 0; j < 8; ++j) {
        float zt = (float)vz[j], it = (float)vi[j], ft = (float)vf[j];
        float z = 1.f - __fdividef(2.f, __expf(2.f * zt) + 1.f);
        float mn = fmaxf(ft + m, it);
        float ih = __expf(it - mn);
        float fh = __expf(ft + m - mn);
        c = fh * c + ih * z;
        n = fh * n + ih;
        m = mn;
        sf += ft;
      }
    }
    // --- seg 2sp+1 (buffer B)
    {
      f16x8 vz = bzB, vi = biB, vf = bfB;
      if (sp < 3) {
        bzB = *(const f16x8*)(gz + (sp * 2 + 3) * 8);
        biB = *(const f16x8*)(gi + (sp * 2 + 3) * 8);
        bfB = *(const f16x8*)(gf + (sp * 2 + 3) * 8);
      }
#pragma unroll
      for (int j = 0; j < 8; ++j) {
        float zt = (float)vz[j], it = (float)vi[j], ft = (float)vf[j];
        float z = 1.f - __fdividef(2.f, __expf(2.f * zt) + 1.f);
        float mn = fmaxf(ft + m, it);
        float ih = __expf(it - mn);
        float fh = __expf(ft + m - mn);
        c = fh * c + ih * z;
        n = fh * n + ih;
        m = mn;
        sf += ft;
      }
    }
  }
  summ[(size_t)kc * CH + chan] = f32x4{sf, c, n, m};
}

__global__ __launch_bounds__(256) void scan_apply_g(const _Float16* __restrict__ Gt,
                                                    const f32x4* __restrict__ states,
                                                    float* __restrict__ out) {
  __shared__ float Ls[16 * 256];   // 16 KB out-staging tile
  int kc = blockIdx.x >> 5;
  int cb = blockIdx.x & 31;
  int b = cb >> 2, d0 = (cb & 3) << 8;
  int tid = threadIdx.x, lane = tid & 63, w = tid >> 6;
  int chan = (b << 10) + d0 + tid;
  const _Float16* gz = Gt + ((size_t)chan << 12) + kc * LCH;
  const _Float16* gi = gz + G_PLANE;
  const _Float16* gf = gz + 2 * G_PLANE;
  const _Float16* go = gz + 3 * G_PLANE;
  float* ob = out + (size_t)(b * 4096 + kc * LCH) * 1024 + d0;

  f32x4 stv = states[(size_t)kc * CH + chan];
  float c = stv.x, n = stv.y, m = stv.z;

  f16x8 bzA = *(const f16x8*)(gz),     bzB = *(const f16x8*)(gz + 8);
  f16x8 biA = *(const f16x8*)(gi),     biB = *(const f16x8*)(gi + 8);
  f16x8 bfA = *(const f16x8*)(gf),     bfB = *(const f16x8*)(gf + 8);
  f16x8 boA = *(const f16x8*)(go),     boB = *(const f16x8*)(go + 8);

  for (int st = 0; st < 4; ++st) {
    // --- seg 2st (buffer A) -> Ls rows 0..7
    {
      f16x8 vz = bzA, vi = biA, vf = bfA, vo = boA;
      if (st < 3) {
        bzA = *(const f16x8*)(gz + (st * 2 + 2) * 8);
        biA = *(const f16x8*)(gi + (st * 2 + 2) * 8);
        bfA = *(const f16x8*)(gf + (st * 2 + 2) * 8);
        boA = *(const f16x8*)(go + (st * 2 + 2) * 8);
      }
#pragma unroll
      for (int j = 0; j < 8; ++j) {
        float zt = (float)vz[j], it = (float)vi[j], ft = (float)vf[j], ot = (float)vo[j];
        float z = 1.f - __fdividef(2.f, __expf(2.f * zt) + 1.f);
        float og = __fdividef(1.f, 1.f + __expf(-ot));
        float mn = fmaxf(ft + m, it);
        float ih = __expf(it - mn);
        float fh = __expf(ft + m - mn);
        c = fh * c + ih * z;
        n = fh * n + ih;
        m = mn;
        Ls[j * 256 + tid] = og * __fdividef(c, n + 1e-8f);
      }
    }
    // --- seg 2st+1 (buffer B) -> Ls rows 8..15
    {
      f16x8 vz = bzB, vi = biB, vf = bfB, vo = boB;
      if (st < 3) {
        bzB = *(const f16x8*)(gz + (st * 2 + 3) * 8);
        biB = *(const f16x8*)(gi + (st * 2 + 3) * 8);
        bfB = *(const f16x8*)(gf + (st * 2 + 3) * 8);
        boB = *(const f16x8*)(go + (st * 2 + 3) * 8);
      }
#pragma unroll
      for (int j = 0; j < 8; ++j) {
        float zt = (float)vz[j], it = (float)vi[j], ft = (float)vf[j], ot = (float)vo[j];
        float z = 1.f - __fdividef(2.f, __expf(2.f * zt) + 1.f);
        float og = __fdividef(1.f, 1.f + __expf(-ot));
        float mn = fmaxf(ft + m, it);
        float ih = __expf(it - mn);
        float fh = __expf(ft + m - mn);
        c = fh * c + ih * z;
        n = fh * n + ih;
        m = mn;
        Ls[(8 + j) * 256 + tid] = og * __fdividef(c, n + 1e-8f);
      }
    }
    __syncthreads();
    // coalesced flush: wave w -> rows w*4..w*4+3; 1KB contiguous per row
#pragma unroll
    for (int r = 0; r < 4; ++r) {
      int tt = (w << 2) + r;
      f32x4 v = *(const f32x4*)&Ls[tt * 256 + (lane << 2)];
      *(f32x4*)&ob[(size_t)(st * 16 + tt) * 1024 + (lane << 2)] = v;
    }
    __syncthreads();
  }
}

// ---- sequential combine over chunks; init (c,n,m)=(0,0,0) matches reference
__global__ __launch_bounds__(256) void scan_combine(const f32x4* __restrict__ summ,
                                                    f32x4* __restrict__ states) {
  int chan = blockIdx.x * 256 + threadIdx.x;
  float c = 0.f, n = 0.f, m = 0.f;
#pragma unroll 4
  for (int kc = 0; kc < KCH; ++kc) {
    states[(size_t)kc * CH + chan] = f32x4{c, n, m, 0.f};
    f32x4 sm = summ[(size_t)kc * CH + chan];  // (sf, c_loc, n_loc, m_loc)
    float mn = fmaxf(m + sm.x, sm.w);
    float ea = __expf(m + sm.x - mn);
    float eb = __expf(sm.w - mn);
    c = ea * c + eb * sm.y;
    n = ea * n + eb * sm.z;
    m = mn;
  }
}

extern "C" void kernel_launch(void* const* d_in, const int* in_sizes, int n_in,
                              void* d_out, int out_size, void* d_ws, size_t ws_size,
                              hipStream_t stream) {
  const float* x  = (const float*)d_in[0];
  const float* Wz = (const float*)d_in[1];
  const float* Wi = (const float*)d_in[2];
  const float* Wf = (const float*)d_in[3];
  const float* Wo = (const float*)d_in[4];
  float* out = (float*)d_out;

  char* ws = (char*)d_ws;
  _Float16* Whf = (_Float16*)(ws);
  f32x4* summ   = (f32x4*)(ws + 4194304);
  f32x4* states = (f32x4*)(ws + 12582912);
  _Float16* Gt  = (_Float16*)(ws + G_OFF);

  cvt_w<<<1024, 256, 0, stream>>>(Wz, Wi, Wf, Wo, Whf);
  gemm_f16<<<8192, 512, 32768, stream>>>(x, Whf, Gt);
  scan_partial_g<<<2048, 256, 0, stream>>>(Gt, summ);
  scan_combine<<<32, 256, 0, stream>>>(summ, states);
  scan_apply_g<<<2048, 256, 0, stream>>>(Gt, states, out);
}

// Round 10
// 687.666 us; speedup vs baseline: 1.0582x; 1.0582x over previous
//
#include <hip/hip_runtime.h>
#include <hip/hip_bf16.h>

typedef __attribute__((ext_vector_type(4))) float f32x4;
typedef __attribute__((ext_vector_type(8))) _Float16 f16x8;
typedef __attribute__((ext_vector_type(4))) _Float16 f16x4;

constexpr int KCH = 64;   // chunks over S=4096
constexpr int LCH = 64;   // steps per chunk
constexpr int CH  = 8192; // channels = B*D

// ---------- ws layout (bytes), ~289 MB (proven available) ----------
// Whf f16 [g][h][o][k]: 0        .. +2097152
// summ f32x4[64][8192]: 4194304  .. +8388608
// states:               12582912 .. +8388608
// Gt f16 4 planes [chan=8192][t=4096]: 20971520 .. +268435456
constexpr size_t G_OFF   = 20971520;
constexpr size_t G_PLANE = 33554432;  // f16 elems per plane

__global__ __launch_bounds__(256) void cvt_w(const float* __restrict__ Wz,
                                             const float* __restrict__ Wi,
                                             const float* __restrict__ Wf,
                                             const float* __restrict__ Wo,
                                             _Float16* __restrict__ Whf) {
  int i = blockIdx.x * 256 + threadIdx.x;
  int flat = i << 2;
  int g = flat >> 18;
  int rest = flat & 262143;                 // [h][o][k]
  const float* src = (g == 0) ? Wz : (g == 1) ? Wi : (g == 2) ? Wf : Wo;
  f32x4 v = *(const f32x4*)(src + rest);
  f16x4 h;
#pragma unroll
  for (int j = 0; j < 4; ++j) h[j] = (_Float16)v[j];
  *(f16x4*)(Whf + flat) = h;
}

// ======================= gate GEMM (single f16) =======================
// Proven structure (R6: 190us, ideal FETCH/WRITE); epilogue packs 4
// row-consecutive acc elems -> f16x4 8B store into channel-major Gt[g][chan][t]
// (proven correct in R9).
__global__ __launch_bounds__(512, 6)
void gemm_f16(const float* __restrict__ x,
              const _Float16* __restrict__ Whf,
              _Float16* __restrict__ Gt) {
  extern __shared__ _Float16 sm[];
  _Float16* Af = sm;           // [128][8 chunks of 8 f16], 16 KB
  _Float16* Bf = sm + 8192;    // same, 16 KB

  int bid = blockIdx.x;                       // 8192
  int mt = (bid & 7) + ((bid >> 8) << 3);     // 0..255
  int s  = (bid >> 3) & 31;
  int g  = s & 3;
  int dt = s >> 2;                            // 0..7 -> d0 = dt*128
  int r0 = mt << 7;
  int d0 = dt << 7;
  int h  = d0 >> 8;                           // head of this d-block
  int o0 = d0 & 255;

  int tid = threadIdx.x, lane = tid & 63, wid = tid >> 6;
  int wm = wid >> 1, wn = wid & 1;            // 4m x 2n -> wave tile 32r x 64d
  int lr = lane & 15, hi2 = lane >> 4;

  const _Float16* wB = Whf + (((size_t)((g << 2) | h)) << 16);  // [256 o][256 k]

  int arow = tid >> 2;                // 4 threads per A-row
  int kq   = (tid & 3) << 4;          // 16-float k-offset
  const float* xrow = x + (size_t)(r0 + arow) * 1024 + (h << 8) + kq;

  f32x4 acc[2][4] = {};

  for (int kt = 0; kt < 4; ++kt) {
    int k0 = kt << 6;
    // ---- stage A: fp32 -> f16 -> LDS (swizzled chunks)
    {
      const float* xp = xrow + k0;
#pragma unroll
      for (int p = 0; p < 2; ++p) {
        f32x4 v0 = *(const f32x4*)(xp + p * 8);
        f32x4 v1 = *(const f32x4*)(xp + p * 8 + 4);
        f16x8 hv;
        hv[0] = (_Float16)v0.x; hv[1] = (_Float16)v0.y;
        hv[2] = (_Float16)v0.z; hv[3] = (_Float16)v0.w;
        hv[4] = (_Float16)v1.x; hv[5] = (_Float16)v1.y;
        hv[6] = (_Float16)v1.z; hv[7] = (_Float16)v1.w;
        int kc = (kq >> 3) + p;                    // chunk 0..7
        int cidx = (arow << 3) + (kc ^ (arow & 7));
        *(f16x8*)(Af + cidx * 8) = hv;
      }
    }
    // ---- stage B: global_load_lds, linear dest + inverse-swizzled source
#pragma unroll
    for (int p = 0; p < 2; ++p) {
      int c = (p << 9) + tid;           // 16B-chunk index 0..1023
      int row = c >> 3;                 // B row = d-offset 0..127
      int kcd = (c & 7) ^ (row & 7);
      const _Float16* srcp = wB + (size_t)(o0 + row) * 256 + k0 + (kcd << 3);
      __builtin_amdgcn_global_load_lds(
          (const __attribute__((address_space(1))) void*)srcp,
          (__attribute__((address_space(3))) void*)(Bf + c * 8), 16, 0, 0);
    }
    __syncthreads();
#pragma unroll
    for (int ks = 0; ks < 2; ++ks) {
      int kcf = (ks << 2) + hi2;        // frag chunk 0..7
      f16x8 af[2], bf[4];
#pragma unroll
      for (int mf = 0; mf < 2; ++mf) {
        int row = (wm << 5) + (mf << 4) + lr;
        int cidx = (row << 3) + (kcf ^ (row & 7));
        af[mf] = *(const f16x8*)(Af + cidx * 8);
      }
#pragma unroll
      for (int nf = 0; nf < 4; ++nf) {
        int row = (wn << 6) + (nf << 4) + lr;
        int cidx = (row << 3) + (kcf ^ (row & 7));
        bf[nf] = *(const f16x8*)(Bf + cidx * 8);
      }
#pragma unroll
      for (int mf = 0; mf < 2; ++mf)
#pragma unroll
        for (int nf = 0; nf < 4; ++nf)
          acc[mf][nf] = __builtin_amdgcn_mfma_f32_16x16x32_f16(af[mf], bf[nf],
                                                               acc[mf][nf], 0, 0, 0);
    }
    __syncthreads();
  }
  // ---- epilogue: C/D col=lane&15 (d), row=(lane>>4)*4+j (s). Pack j -> f16x4.
  int bb = r0 >> 12;           // batch (tiles never cross b)
  int sbase = r0 & 4095;
  _Float16* Gg = Gt + (size_t)g * G_PLANE;
#pragma unroll
  for (int mf = 0; mf < 2; ++mf)
#pragma unroll
    for (int nf = 0; nf < 4; ++nf) {
      int d = d0 + (wn << 6) + (nf << 4) + lr;
      int sx = sbase + (wm << 5) + (mf << 4) + (hi2 << 2);
      f16x4 pk;
#pragma unroll
      for (int j = 0; j < 4; ++j) pk[j] = (_Float16)acc[mf][nf][j];
      *(f16x4*)(Gg + (((size_t)((bb << 10) + d)) << 12) + sx) = pk;
    }
}

// ======================= scans over channel-major Gt =======================
// Full 64-step chunk buffered in registers UP-FRONT: every 64B line's four 16B
// touches issue back-to-back -> each line fetched from HBM exactly once
// (fixes R9's 3.1x read amplification from L2-evicted strided streams).
__global__ __launch_bounds__(256, 3) void scan_partial_g(const _Float16* __restrict__ Gt,
                                                         f32x4* __restrict__ summ) {
  int kc = blockIdx.x >> 5;
  int cb = blockIdx.x & 31;
  int chan = cb * 256 + threadIdx.x;
  const _Float16* gz = Gt + ((size_t)chan << 12) + kc * LCH;

  f16x8 bz[8], bi[8], bf[8];
#pragma unroll
  for (int j = 0; j < 8; ++j) bz[j] = *(const f16x8*)(gz + j * 8);
#pragma unroll
  for (int j = 0; j < 8; ++j) bi[j] = *(const f16x8*)(gz + G_PLANE + j * 8);
#pragma unroll
  for (int j = 0; j < 8; ++j) bf[j] = *(const f16x8*)(gz + 2 * G_PLANE + j * 8);

  float m = -INFINITY, c = 0.f, n = 0.f, sf = 0.f;
#pragma unroll
  for (int s8 = 0; s8 < 8; ++s8) {
    f16x8 vz = bz[s8], vi = bi[s8], vf = bf[s8];
#pragma unroll
    for (int j = 0; j < 8; ++j) {
      float zt = (float)vz[j], it = (float)vi[j], ft = (float)vf[j];
      float z = 1.f - __fdividef(2.f, __expf(2.f * zt) + 1.f);
      float mn = fmaxf(ft + m, it);
      float ih = __expf(it - mn);
      float fh = __expf(ft + m - mn);
      c = fh * c + ih * z;
      n = fh * n + ih;
      m = mn;
      sf += ft;
    }
  }
  summ[(size_t)kc * CH + chan] = f32x4{sf, c, n, m};
}

__global__ __launch_bounds__(256, 3) void scan_apply_g(const _Float16* __restrict__ Gt,
                                                       const f32x4* __restrict__ states,
                                                       float* __restrict__ out) {
  int kc = blockIdx.x >> 5;
  int cb = blockIdx.x & 31;
  int chan = cb * 256 + threadIdx.x;
  int b = chan >> 10, d = chan & 1023;
  const _Float16* gz = Gt + ((size_t)chan << 12) + kc * LCH;
  float* op = out + (size_t)(b * 4096 + kc * LCH) * 1024 + d;

  f16x8 bz[8], bi[8], bf[8], bo[8];
#pragma unroll
  for (int j = 0; j < 8; ++j) bz[j] = *(const f16x8*)(gz + j * 8);
#pragma unroll
  for (int j = 0; j < 8; ++j) bi[j] = *(const f16x8*)(gz + G_PLANE + j * 8);
#pragma unroll
  for (int j = 0; j < 8; ++j) bf[j] = *(const f16x8*)(gz + 2 * G_PLANE + j * 8);
#pragma unroll
  for (int j = 0; j < 8; ++j) bo[j] = *(const f16x8*)(gz + 3 * G_PLANE + j * 8);

  f32x4 stv = states[(size_t)kc * CH + chan];
  float c = stv.x, n = stv.y, m = stv.z;

#pragma unroll
  for (int s8 = 0; s8 < 8; ++s8) {
    f16x8 vz = bz[s8], vi = bi[s8], vf = bf[s8], vo = bo[s8];
#pragma unroll
    for (int j = 0; j < 8; ++j) {
      float zt = (float)vz[j], it = (float)vi[j], ft = (float)vf[j], ot = (float)vo[j];
      float z = 1.f - __fdividef(2.f, __expf(2.f * zt) + 1.f);
      float og = __fdividef(1.f, 1.f + __expf(-ot));
      float mn = fmaxf(ft + m, it);
      float ih = __expf(it - mn);
      float fh = __expf(ft + m - mn);
      c = fh * c + ih * z;
      n = fh * n + ih;
      m = mn;
      // 64 lanes -> 256B contiguous per step: fully coalesced
      op[(size_t)(s8 * 8 + j) * 1024] = og * __fdividef(c, n + 1e-8f);
    }
  }
}

// ---- sequential combine over chunks; init (c,n,m)=(0,0,0) matches reference
__global__ __launch_bounds__(256) void scan_combine(const f32x4* __restrict__ summ,
                                                    f32x4* __restrict__ states) {
  int chan = blockIdx.x * 256 + threadIdx.x;
  float c = 0.f, n = 0.f, m = 0.f;
#pragma unroll 4
  for (int kc = 0; kc < KCH; ++kc) {
    states[(size_t)kc * CH + chan] = f32x4{c, n, m, 0.f};
    f32x4 sm = summ[(size_t)kc * CH + chan];  // (sf, c_loc, n_loc, m_loc)
    float mn = fmaxf(m + sm.x, sm.w);
    float ea = __expf(m + sm.x - mn);
    float eb = __expf(sm.w - mn);
    c = ea * c + eb * sm.y;
    n = ea * n + eb * sm.z;
    m = mn;
  }
}

extern "C" void kernel_launch(void* const* d_in, const int* in_sizes, int n_in,
                              void* d_out, int out_size, void* d_ws, size_t ws_size,
                              hipStream_t stream) {
  const float* x  = (const float*)d_in[0];
  const float* Wz = (const float*)d_in[1];
  const float* Wi = (const float*)d_in[2];
  const float* Wf = (const float*)d_in[3];
  const float* Wo = (const float*)d_in[4];
  float* out = (float*)d_out;

  char* ws = (char*)d_ws;
  _Float16* Whf = (_Float16*)(ws);
  f32x4* summ   = (f32x4*)(ws + 4194304);
  f32x4* states = (f32x4*)(ws + 12582912);
  _Float16* Gt  = (_Float16*)(ws + G_OFF);

  cvt_w<<<1024, 256, 0, stream>>>(Wz, Wi, Wf, Wo, Whf);
  gemm_f16<<<8192, 512, 32768, stream>>>(x, Whf, Gt);
  scan_partial_g<<<2048, 256, 0, stream>>>(Gt, summ);
  scan_combine<<<32, 256, 0, stream>>>(summ, states);
  scan_apply_g<<<2048, 256, 0, stream>>>(Gt, states, out);
}

// Round 11
// 540.003 us; speedup vs baseline: 1.3475x; 1.2734x over previous
//
#include <hip/hip_runtime.h>
#include <hip/hip_bf16.h>

typedef __attribute__((ext_vector_type(4))) float f32x4;
typedef __attribute__((ext_vector_type(8))) _Float16 f16x8;
typedef __attribute__((ext_vector_type(4))) _Float16 f16x4;

constexpr int KCH = 64;   // chunks over S=4096
constexpr int LCH = 64;   // steps per chunk
constexpr int CH  = 8192; // channels = B*D

// ---------- ws layout (bytes), ~289 MB (proven available) ----------
// Whf f16 [g][h][o][k]: 0        .. +2097152
// summ f32x4[64][8192]: 4194304  .. +8388608
// states:               12582912 .. +8388608
// Gt f16 4 planes [chan=8192][t=4096]: 20971520 .. +268435456
constexpr size_t G_OFF   = 20971520;
constexpr size_t G_PLANE = 33554432;  // f16 elems per plane

__global__ __launch_bounds__(256) void cvt_w(const float* __restrict__ Wz,
                                             const float* __restrict__ Wi,
                                             const float* __restrict__ Wf,
                                             const float* __restrict__ Wo,
                                             _Float16* __restrict__ Whf) {
  int i = blockIdx.x * 256 + threadIdx.x;
  int flat = i << 2;
  int g = flat >> 18;
  int rest = flat & 262143;                 // [h][o][k]
  const float* src = (g == 0) ? Wz : (g == 1) ? Wi : (g == 2) ? Wf : Wo;
  f32x4 v = *(const f32x4*)(src + rest);
  f16x4 h;
#pragma unroll
  for (int j = 0; j < 4; ++j) h[j] = (_Float16)v[j];
  *(f16x4*)(Whf + flat) = h;
}

// ======================= gate GEMM (single f16) =======================
// Proven structure (R6: 190us, ideal FETCH/WRITE); epilogue packs 4
// row-consecutive acc elems -> f16x4 8B store into channel-major Gt[g][chan][t].
__global__ __launch_bounds__(512, 6)
void gemm_f16(const float* __restrict__ x,
              const _Float16* __restrict__ Whf,
              _Float16* __restrict__ Gt) {
  extern __shared__ _Float16 sm[];
  _Float16* Af = sm;           // [128][8 chunks of 8 f16], 16 KB
  _Float16* Bf = sm + 8192;    // same, 16 KB

  int bid = blockIdx.x;                       // 8192
  int mt = (bid & 7) + ((bid >> 8) << 3);     // 0..255
  int s  = (bid >> 3) & 31;
  int g  = s & 3;
  int dt = s >> 2;                            // 0..7 -> d0 = dt*128
  int r0 = mt << 7;
  int d0 = dt << 7;
  int h  = d0 >> 8;                           // head of this d-block
  int o0 = d0 & 255;

  int tid = threadIdx.x, lane = tid & 63, wid = tid >> 6;
  int wm = wid >> 1, wn = wid & 1;            // 4m x 2n -> wave tile 32r x 64d
  int lr = lane & 15, hi2 = lane >> 4;

  const _Float16* wB = Whf + (((size_t)((g << 2) | h)) << 16);  // [256 o][256 k]

  int arow = tid >> 2;                // 4 threads per A-row
  int kq   = (tid & 3) << 4;          // 16-float k-offset
  const float* xrow = x + (size_t)(r0 + arow) * 1024 + (h << 8) + kq;

  f32x4 acc[2][4] = {};

  for (int kt = 0; kt < 4; ++kt) {
    int k0 = kt << 6;
    // ---- stage A: fp32 -> f16 -> LDS (swizzled chunks)
    {
      const float* xp = xrow + k0;
#pragma unroll
      for (int p = 0; p < 2; ++p) {
        f32x4 v0 = *(const f32x4*)(xp + p * 8);
        f32x4 v1 = *(const f32x4*)(xp + p * 8 + 4);
        f16x8 hv;
        hv[0] = (_Float16)v0.x; hv[1] = (_Float16)v0.y;
        hv[2] = (_Float16)v0.z; hv[3] = (_Float16)v0.w;
        hv[4] = (_Float16)v1.x; hv[5] = (_Float16)v1.y;
        hv[6] = (_Float16)v1.z; hv[7] = (_Float16)v1.w;
        int kc = (kq >> 3) + p;                    // chunk 0..7
        int cidx = (arow << 3) + (kc ^ (arow & 7));
        *(f16x8*)(Af + cidx * 8) = hv;
      }
    }
    // ---- stage B: global_load_lds, linear dest + inverse-swizzled source
#pragma unroll
    for (int p = 0; p < 2; ++p) {
      int c = (p << 9) + tid;           // 16B-chunk index 0..1023
      int row = c >> 3;                 // B row = d-offset 0..127
      int kcd = (c & 7) ^ (row & 7);
      const _Float16* srcp = wB + (size_t)(o0 + row) * 256 + k0 + (kcd << 3);
      __builtin_amdgcn_global_load_lds(
          (const __attribute__((address_space(1))) void*)srcp,
          (__attribute__((address_space(3))) void*)(Bf + c * 8), 16, 0, 0);
    }
    __syncthreads();
#pragma unroll
    for (int ks = 0; ks < 2; ++ks) {
      int kcf = (ks << 2) + hi2;        // frag chunk 0..7
      f16x8 af[2], bf[4];
#pragma unroll
      for (int mf = 0; mf < 2; ++mf) {
        int row = (wm << 5) + (mf << 4) + lr;
        int cidx = (row << 3) + (kcf ^ (row & 7));
        af[mf] = *(const f16x8*)(Af + cidx * 8);
      }
#pragma unroll
      for (int nf = 0; nf < 4; ++nf) {
        int row = (wn << 6) + (nf << 4) + lr;
        int cidx = (row << 3) + (kcf ^ (row & 7));
        bf[nf] = *(const f16x8*)(Bf + cidx * 8);
      }
#pragma unroll
      for (int mf = 0; mf < 2; ++mf)
#pragma unroll
        for (int nf = 0; nf < 4; ++nf)
          acc[mf][nf] = __builtin_amdgcn_mfma_f32_16x16x32_f16(af[mf], bf[nf],
                                                               acc[mf][nf], 0, 0, 0);
    }
    __syncthreads();
  }
  // ---- epilogue: C/D col=lane&15 (d), row=(lane>>4)*4+j (s). Pack j -> f16x4.
  int bb = r0 >> 12;           // batch (tiles never cross b)
  int sbase = r0 & 4095;
  _Float16* Gg = Gt + (size_t)g * G_PLANE;
#pragma unroll
  for (int mf = 0; mf < 2; ++mf)
#pragma unroll
    for (int nf = 0; nf < 4; ++nf) {
      int d = d0 + (wn << 6) + (nf << 4) + lr;
      int sx = sbase + (wm << 5) + (mf << 4) + (hi2 << 2);
      f16x4 pk;
#pragma unroll
      for (int j = 0; j < 4; ++j) pk[j] = (_Float16)acc[mf][nf][j];
      *(f16x4*)(Gg + (((size_t)((bb << 10) + d)) << 12) + sx) = pk;
    }
}

// ======================= scans over channel-major Gt =======================
// All chunk loads issued back-to-back, then sched_barrier(0) fences the
// scheduler so consumption cannot interleave: every 128B line's touches are
// simultaneously outstanding -> TCC merges them -> one HBM fetch per line
// regardless of (4MB/XCD) L2 residency. Fixes R10's 2.2x read amplification
// (R10: VGPR=32 proved the compiler dissolved the buffers and re-spread loads).
__global__ __launch_bounds__(256, 3) void scan_partial_g(const _Float16* __restrict__ Gt,
                                                         f32x4* __restrict__ summ) {
  int kc = blockIdx.x >> 5;
  int cb = blockIdx.x & 31;
  int chan = cb * 256 + threadIdx.x;
  const _Float16* gz = Gt + ((size_t)chan << 12) + kc * LCH;

  f16x8 bz[8], bi[8], bf[8];
#pragma unroll
  for (int j = 0; j < 8; ++j) bz[j] = *(const f16x8*)(gz + j * 8);
#pragma unroll
  for (int j = 0; j < 8; ++j) bi[j] = *(const f16x8*)(gz + G_PLANE + j * 8);
#pragma unroll
  for (int j = 0; j < 8; ++j) bf[j] = *(const f16x8*)(gz + 2 * G_PLANE + j * 8);
  __builtin_amdgcn_sched_barrier(0);   // loads stay clustered above this line

  float m = -INFINITY, c = 0.f, n = 0.f, sf = 0.f;
#pragma unroll
  for (int s8 = 0; s8 < 8; ++s8) {
    f16x8 vz = bz[s8], vi = bi[s8], vf = bf[s8];
#pragma unroll
    for (int j = 0; j < 8; ++j) {
      float zt = (float)vz[j], it = (float)vi[j], ft = (float)vf[j];
      float z = 1.f - __fdividef(2.f, __expf(2.f * zt) + 1.f);
      float mn = fmaxf(ft + m, it);
      float ih = __expf(it - mn);
      float fh = __expf(ft + m - mn);
      c = fh * c + ih * z;
      n = fh * n + ih;
      m = mn;
      sf += ft;
    }
  }
  summ[(size_t)kc * CH + chan] = f32x4{sf, c, n, m};
}

__global__ __launch_bounds__(256, 3) void scan_apply_g(const _Float16* __restrict__ Gt,
                                                       const f32x4* __restrict__ states,
                                                       float* __restrict__ out) {
  int kc = blockIdx.x >> 5;
  int cb = blockIdx.x & 31;
  int chan = cb * 256 + threadIdx.x;
  int b = chan >> 10, d = chan & 1023;
  const _Float16* gz = Gt + ((size_t)chan << 12) + kc * LCH;
  float* op = out + (size_t)(b * 4096 + kc * LCH) * 1024 + d;

  f16x8 bz[8], bi[8], bf[8], bo[8];
#pragma unroll
  for (int j = 0; j < 8; ++j) bz[j] = *(const f16x8*)(gz + j * 8);
#pragma unroll
  for (int j = 0; j < 8; ++j) bi[j] = *(const f16x8*)(gz + G_PLANE + j * 8);
#pragma unroll
  for (int j = 0; j < 8; ++j) bf[j] = *(const f16x8*)(gz + 2 * G_PLANE + j * 8);
#pragma unroll
  for (int j = 0; j < 8; ++j) bo[j] = *(const f16x8*)(gz + 3 * G_PLANE + j * 8);
  __builtin_amdgcn_sched_barrier(0);   // loads stay clustered above this line

  f32x4 stv = states[(size_t)kc * CH + chan];
  float c = stv.x, n = stv.y, m = stv.z;

#pragma unroll
  for (int s8 = 0; s8 < 8; ++s8) {
    f16x8 vz = bz[s8], vi = bi[s8], vf = bf[s8], vo = bo[s8];
#pragma unroll
    for (int j = 0; j < 8; ++j) {
      float zt = (float)vz[j], it = (float)vi[j], ft = (float)vf[j], ot = (float)vo[j];
      float z = 1.f - __fdividef(2.f, __expf(2.f * zt) + 1.f);
      float og = __fdividef(1.f, 1.f + __expf(-ot));
      float mn = fmaxf(ft + m, it);
      float ih = __expf(it - mn);
      float fh = __expf(ft + m - mn);
      c = fh * c + ih * z;
      n = fh * n + ih;
      m = mn;
      // 64 lanes -> 256B contiguous per step: fully coalesced
      op[(size_t)(s8 * 8 + j) * 1024] = og * __fdividef(c, n + 1e-8f);
    }
  }
}

// ---- sequential combine over chunks; init (c,n,m)=(0,0,0) matches reference
__global__ __launch_bounds__(256) void scan_combine(const f32x4* __restrict__ summ,
                                                    f32x4* __restrict__ states) {
  int chan = blockIdx.x * 256 + threadIdx.x;
  float c = 0.f, n = 0.f, m = 0.f;
#pragma unroll 4
  for (int kc = 0; kc < KCH; ++kc) {
    states[(size_t)kc * CH + chan] = f32x4{c, n, m, 0.f};
    f32x4 sm = summ[(size_t)kc * CH + chan];  // (sf, c_loc, n_loc, m_loc)
    float mn = fmaxf(m + sm.x, sm.w);
    float ea = __expf(m + sm.x - mn);
    float eb = __expf(sm.w - mn);
    c = ea * c + eb * sm.y;
    n = ea * n + eb * sm.z;
    m = mn;
  }
}

extern "C" void kernel_launch(void* const* d_in, const int* in_sizes, int n_in,
                              void* d_out, int out_size, void* d_ws, size_t ws_size,
                              hipStream_t stream) {
  const float* x  = (const float*)d_in[0];
  const float* Wz = (const float*)d_in[1];
  const float* Wi = (const float*)d_in[2];
  const float* Wf = (const float*)d_in[3];
  const float* Wo = (const float*)d_in[4];
  float* out = (float*)d_out;

  char* ws = (char*)d_ws;
  _Float16* Whf = (_Float16*)(ws);
  f32x4* summ   = (f32x4*)(ws + 4194304);
  f32x4* states = (f32x4*)(ws + 12582912);
  _Float16* Gt  = (_Float16*)(ws + G_OFF);

  cvt_w<<<1024, 256, 0, stream>>>(Wz, Wi, Wf, Wo, Whf);
  gemm_f16<<<8192, 512, 32768, stream>>>(x, Whf, Gt);
  scan_partial_g<<<2048, 256, 0, stream>>>(Gt, summ);
  scan_combine<<<32, 256, 0, stream>>>(summ, states);
  scan_apply_g<<<2048, 256, 0, stream>>>(Gt, states, out);
}